// Round 12
// baseline (264.128 us; speedup 1.0000x reference)
//
#include <hip/hip_runtime.h>
#include <hip/hip_fp16.h>

// ---------------------------------------------------------------------------
// GNN_20237885899323: 2-layer GCN + mean-pool + MLP head, fp32 compute.
// Round 12: r11 left k_agg32x issue-bound (VALUBusy 52%, FETCH 15.8MB): 8
// lanes recompute each src's 32 features per EDGE (~32x redundancy/node).
// Fix: precompute h~0 once per node as fp16 [N,32] (6.4MB) in passB's
// epilogue; layer 1 becomes a 64B-row fp16 gather -- a half-size clone of the
// validated k_agg64h (16 rows/instr, fp32 accum, fused @w1 epilogue).
// Trades FETCH 15.8->~100MB for ~2.4x fewer lane-ops/edge.
// Error: +fp16 on h~0 -> predicted absmax ~1e-4 vs 2.12e-4 gate.
// ---------------------------------------------------------------------------

#define NBMAX 512
#define BCAP 12288
#define CAPL 10240

__global__ void k_initcur(int* __restrict__ bcur) {
    bcur[threadIdx.x] = threadIdx.x * BCAP;  // 512 threads
}

__global__ void k_passA(const int* __restrict__ ei, int* __restrict__ bcur,
                        unsigned int* __restrict__ pairBuf, int E) {
    __shared__ int h[NBMAX];
    __shared__ int base[NBMAX];
    const int T = 256, EPT = 32;
    int chunk = blockIdx.x * (T * EPT);
    int t = threadIdx.x;
    h[t] = 0; h[t + 256] = 0;
    __syncthreads();
    int nE = min(E - chunk, T * EPT);
    for (int i = t; i < nE; i += T)
        atomicAdd(&h[ei[E + chunk + i] >> 8], 1);
    __syncthreads();
    for (int bb = t; bb < NBMAX; bb += T) {
        int c = h[bb];
        base[bb] = c > 0 ? atomicAdd(&bcur[bb], c) : 0;
        h[bb] = 0;
    }
    __syncthreads();
    for (int i = t; i < nE; i += T) {
        int s = ei[chunk + i];
        int d = ei[E + chunk + i];
        int bb = d >> 8;
        int pos = base[bb] + atomicAdd(&h[bb], 1);
        pairBuf[pos] = ((unsigned int)(d & 255) << 24) | (unsigned int)s;  // cached: L2 merges
    }
}

// pass B: per-bucket counting sort -> rowPtr, dis, srcIdx, and fp16
// h~0[n] = dis*relu(x@wn+bn) for this block's 256 nodes.
__global__ void k_passB(const int* __restrict__ bcur,
                        const unsigned int* __restrict__ pairBuf,
                        int* __restrict__ rowPtr, float* __restrict__ dis,
                        int* __restrict__ srcIdx, const float* __restrict__ x,
                        const float* __restrict__ wn, const float* __restrict__ bn,
                        __half* __restrict__ h0, int N, int E) {
    __shared__ unsigned int eLds[CAPL];
    __shared__ int hist[256];
    __shared__ int scan[256];
    int b = blockIdx.x;
    int t = threadIdx.x;  // 256
    int count = bcur[b] - b * BCAP;
    const unsigned int* src = pairBuf + (size_t)b * BCAP;
    // gbase = sum of bucket counts below b (redundant per-block reduce)
    int part = 0;
    for (int i = t; i < b; i += 256) part += bcur[i] - i * BCAP;
    scan[t] = part;
    __syncthreads();
    for (int o = 128; o > 0; o >>= 1) {
        if (t < o) scan[t] += scan[t + o];
        __syncthreads();
    }
    int gbase = scan[0];
    __syncthreads();
    hist[t] = 0;
    int nStage = min(count, CAPL);
    for (int i = t; i < nStage; i += 256) eLds[i] = __builtin_nontemporal_load(src + i);
    __syncthreads();
    for (int i = t; i < nStage; i += 256) atomicAdd(&hist[eLds[i] >> 24], 1);
    for (int i = CAPL + t; i < count; i += 256)
        atomicAdd(&hist[__builtin_nontemporal_load(src + i) >> 24], 1);
    __syncthreads();
    int c = hist[t];
    scan[t] = c;
    __syncthreads();
    for (int o = 1; o < 256; o <<= 1) {
        int v = (t >= o) ? scan[t - o] : 0;
        __syncthreads();
        scan[t] += v;
        __syncthreads();
    }
    int excl = scan[t] - c;
    int node = (b << 8) + t;
    float dval = rsqrtf((float)c + 1.0f);  // +1 self loop
    if (node < N) {
        rowPtr[node] = gbase + excl;
        dis[node] = dval;
        if (node == N - 1) rowPtr[N] = E;
    }
    hist[t] = excl;
    __syncthreads();
    for (int i = t; i < nStage; i += 256) {
        unsigned int e = eLds[i];
        int pos = atomicAdd(&hist[e >> 24], 1);
        srcIdx[gbase + pos] = (int)(e & 0xFFFFFFu);  // cached: clustered, L2 merges
    }
    for (int i = CAPL + t; i < count; i += 256) {
        unsigned int e = __builtin_nontemporal_load(src + i);
        int pos = atomicAdd(&hist[e >> 24], 1);
        srcIdx[gbase + pos] = (int)(e & 0xFFFFFFu);
    }
    // ---- fp16 h~0 epilogue: this thread's own node, 32 features ----
    if (node < N) {
        float x0 = x[2 * node], x1 = x[2 * node + 1];
        __half2 hv[16];
#pragma unroll
        for (int j = 0; j < 32; j += 2) {
            float v0 = fmaf(x0, wn[j],     fmaf(x1, wn[32 + j],     bn[j]));
            float v1 = fmaf(x0, wn[j + 1], fmaf(x1, wn[32 + j + 1], bn[j + 1]));
            v0 = fmaxf(v0, 0.f) * dval;
            v1 = fmaxf(v1, 0.f) * dval;
            hv[j >> 1] = __floats2half2_rn(v0, v1);
        }
        float4* dst = (float4*)(h0 + (size_t)node * 32);
        const float4* sv = (const float4*)hv;
#pragma unroll
        for (int k = 0; k < 4; ++k) dst[k] = sv[k];
    }
}

// layer 1: gather fp16 h~0 rows (64 B, 6.4 MB working set); fp32 accumulate;
// butterfly reduce over 16 row groups; fused @w1 epilogue -> fp16 h~1.
__global__ void k_agg32f(const int* __restrict__ rowPtr, const int* __restrict__ srcIdx,
                         const __half* __restrict__ y, const float* __restrict__ dis,
                         const float* __restrict__ w1, const float* __restrict__ b1,
                         __half* __restrict__ hOut, int N) {
    constexpr int RPI = 16, U = 2, CH = RPI * U;  // 32 rows per iter
    int wid = (blockIdx.x * blockDim.x + threadIdx.x) >> 6;
    if (wid >= N) return;
    int lane = threadIdx.x & 63;
    int q = lane & 3;   // 16-byte chunk: features 8q..8q+7
    int r = lane >> 2;  // row group 0..15
    const float4* yq = (const float4*)y;  // one row = 4 float4 (32 halves)
    float acc[8] = {0.f, 0.f, 0.f, 0.f, 0.f, 0.f, 0.f, 0.f};
    if (r == 0) {  // self row
        float4 a = yq[(size_t)wid * 4 + q];
        union { float4 f4; __half2 h2[4]; } cv; cv.f4 = a;
#pragma unroll
        for (int j = 0; j < 4; ++j) {
            float2 f = __half22float2(cv.h2[j]);
            acc[2 * j] = f.x; acc[2 * j + 1] = f.y;
        }
    }
    int beg = rowPtr[wid], end = rowPtr[wid + 1];
    if (end > beg) {
        int last = end - 1;
        for (int base = beg; base < end; base += CH) {
            int s[U];
            float m[U];
#pragma unroll
            for (int u = 0; u < U; ++u) {
                int i = base + r + u * RPI;
                m[u] = (i < end) ? 1.f : 0.f;
                s[u] = __builtin_nontemporal_load(srcIdx + min(i, last));
            }
#pragma unroll
            for (int u = 0; u < U; ++u) {
                float4 a = yq[(size_t)s[u] * 4 + q];
                union { float4 f4; __half2 h2[4]; } cv; cv.f4 = a;
#pragma unroll
                for (int j = 0; j < 4; ++j) {
                    float2 f = __half22float2(cv.h2[j]);
                    acc[2 * j]     = fmaf(f.x, m[u], acc[2 * j]);
                    acc[2 * j + 1] = fmaf(f.y, m[u], acc[2 * j + 1]);
                }
            }
        }
    }
#pragma unroll
    for (int mk = 4; mk < 64; mk <<= 1) {
#pragma unroll
        for (int j = 0; j < 8; ++j) acc[j] += __shfl_xor(acc[j], mk);
    }
    // every lane holds the reduced 8 features for its chunk q; lane q2 (r=0)
    // broadcasts chunk q2. Fused matmul: s = agg @ w1 column f (f = lane).
    int f = lane;
    float s = 0.f;
#pragma unroll
    for (int q2 = 0; q2 < 4; ++q2) {
#pragma unroll
        for (int j = 0; j < 8; ++j) {
            float bv = __shfl(acc[j], q2);
            s = fmaf(bv, w1[(8 * q2 + j) * 64 + f], s);
        }
    }
    float dv = dis[wid];
    float h = fmaxf(fmaf(dv, s, b1[f]), 0.f) * dv;
    hOut[(size_t)wid * 64 + f] = __float2half(h);
}

// layer 2 aggregation over FP16 rows (128 B): one wave per dst node (r11).
__global__ void k_agg64h(const int* __restrict__ rowPtr, const int* __restrict__ srcIdx,
                         const __half* __restrict__ y, const float* __restrict__ dis,
                         float* __restrict__ z, int N) {
    constexpr int RPI = 8, U = 4, CH = RPI * U;  // 32 rows per iter
    int wid = (blockIdx.x * blockDim.x + threadIdx.x) >> 6;
    if (wid >= N) return;
    int lane = threadIdx.x & 63;
    int q = lane & 7;   // 16-byte chunk: features 8q..8q+7
    int r = lane >> 3;  // row group 0..7
    const float4* yq = (const float4*)y;  // one row = 8 float4 (64 halves)
    float acc[8] = {0.f, 0.f, 0.f, 0.f, 0.f, 0.f, 0.f, 0.f};
    if (r == 0) {  // self row
        float4 a = yq[(size_t)wid * 8 + q];
        union { float4 f4; __half2 h2[4]; } cv; cv.f4 = a;
#pragma unroll
        for (int j = 0; j < 4; ++j) {
            float2 f = __half22float2(cv.h2[j]);
            acc[2 * j] = f.x; acc[2 * j + 1] = f.y;
        }
    }
    int beg = rowPtr[wid], end = rowPtr[wid + 1];
    if (end > beg) {
        int last = end - 1;
        for (int base = beg; base < end; base += CH) {
            int s[U];
            float m[U];
#pragma unroll
            for (int u = 0; u < U; ++u) {
                int i = base + r + u * RPI;
                m[u] = (i < end) ? 1.f : 0.f;
                s[u] = __builtin_nontemporal_load(srcIdx + min(i, last));
            }
#pragma unroll
            for (int u = 0; u < U; ++u) {
                float4 a = yq[(size_t)s[u] * 8 + q];
                union { float4 f4; __half2 h2[4]; } cv; cv.f4 = a;
#pragma unroll
                for (int j = 0; j < 4; ++j) {
                    float2 f = __half22float2(cv.h2[j]);
                    acc[2 * j]     = fmaf(f.x, m[u], acc[2 * j]);
                    acc[2 * j + 1] = fmaf(f.y, m[u], acc[2 * j + 1]);
                }
            }
        }
    }
#pragma unroll
    for (int mk = 8; mk < 64; mk <<= 1) {
#pragma unroll
        for (int j = 0; j < 8; ++j) acc[j] += __shfl_xor(acc[j], mk);
    }
    if (r == 0) {
        float dv = dis[wid];
        float4 o0 = {acc[0] * dv, acc[1] * dv, acc[2] * dv, acc[3] * dv};
        float4 o1 = {acc[4] * dv, acc[5] * dv, acc[6] * dv, acc[7] * dv};
        float4* zp = (float4*)(z + (size_t)wid * 64 + q * 8);
        zp[0] = o0;  // plain store: stays in L2 for poolhead
        zp[1] = o1;
    }
}

// block-per-graph (256 thr): binary-search node range in sorted batch;
// h2 = relu(z2@w2+b2) on the fly (w2 column in VGPRs); mean; MLP head.
__global__ void k_poolhead(const float* __restrict__ z2, const float* __restrict__ w2,
                           const float* __restrict__ b2, const int* __restrict__ batch,
                           const float* __restrict__ wf1, const float* __restrict__ bf1,
                           const float* __restrict__ wf2, const float* __restrict__ bf2,
                           float* __restrict__ out, int N) {
    __shared__ float red[4][64];
    __shared__ float pooled[64];
    __shared__ float gv[32];
    __shared__ int range[2];
    int g = blockIdx.x;
    int t = threadIdx.x;  // 256
    if (t < 2) {
        int target = g + t;
        int lo = 0, hi = N;
        while (lo < hi) {
            int mid = (lo + hi) >> 1;
            if (batch[mid] < target) lo = mid + 1; else hi = mid;
        }
        range[t] = lo;
    }
    __syncthreads();
    int s = range[0], e = range[1];
    int w = t >> 6, f = t & 63;
    float wcol[64];
#pragma unroll
    for (int k = 0; k < 64; ++k) wcol[k] = w2[k * 64 + f];
    float bf = b2[f];
    float acc = 0.f;
    for (int n = s + w; n < e; n += 4) {
        const float4* zr = (const float4*)(z2 + (size_t)n * 64);
        float h = bf;
#pragma unroll
        for (int kq = 0; kq < 16; ++kq) {
            float4 zv = zr[kq];
            h += zv.x * wcol[4 * kq + 0];
            h += zv.y * wcol[4 * kq + 1];
            h += zv.z * wcol[4 * kq + 2];
            h += zv.w * wcol[4 * kq + 3];
        }
        acc += fmaxf(h, 0.f);
    }
    red[w][f] = acc;
    __syncthreads();
    if (t < 64) {
        float c = (float)(e - s);
        c = c > 1.f ? c : 1.f;
        pooled[t] = (red[0][t] + red[1][t] + red[2][t] + red[3][t]) / c;
    }
    __syncthreads();
    if (t < 32) {
        float sv = bf1[t];
#pragma unroll
        for (int k = 0; k < 64; ++k) sv += pooled[k] * wf1[k * 32 + t];
        gv[t] = fmaxf(sv, 0.f);
    }
    __syncthreads();
    if (t == 0) {
        float sv = bf2[0];
#pragma unroll
        for (int j = 0; j < 32; ++j) sv += gv[j] * wf2[j];
        out[g] = sv;
    }
}

extern "C" void kernel_launch(void* const* d_in, const int* in_sizes, int n_in,
                              void* d_out, int out_size, void* d_ws, size_t ws_size,
                              hipStream_t stream) {
    const float* x      = (const float*)d_in[0];
    const int*   ei     = (const int*)d_in[2];
    const int*   batch  = (const int*)d_in[3];
    const float* w_node = (const float*)d_in[4];
    const float* b_node = (const float*)d_in[5];
    const float* w1  = (const float*)d_in[8];
    const float* b1  = (const float*)d_in[9];
    const float* w2  = (const float*)d_in[10];
    const float* b2  = (const float*)d_in[11];
    const float* wf1 = (const float*)d_in[12];
    const float* bf1 = (const float*)d_in[13];
    const float* wf2 = (const float*)d_in[14];
    const float* bf2 = (const float*)d_in[15];
    float* out = (float*)d_out;

    const int N = in_sizes[0] / 2;  // 100000
    const int E = in_sizes[2] / 2;  // 3200000
    const int G = out_size;         // 1024
    const int NB = (N + 255) >> 8;  // 391

    auto align256 = [](size_t v) { return (v + 255) & ~(size_t)255; };
    char* ws = (char*)d_ws;
    size_t off = 0;
    float*  dis     = (float*)(ws + off);  off += align256((size_t)N * 4);
    int*    rowPtr  = (int*)(ws + off);    off += align256((size_t)(N + 1) * 4);
    int*    bcur    = (int*)(ws + off);    off += align256((size_t)NBMAX * 4);
    int*    srcIdx  = (int*)(ws + off);    off += align256((size_t)E * 4);
    float*  region1 = (float*)(ws + off);  off += align256((size_t)N * 64 * 4);  // pairBuf, then z2
    __half* hT1     = (__half*)(ws + off); off += align256((size_t)N * 64 * 2);  // h~1 [N,64] fp16
    __half* h0h     = (__half*)(ws + off); off += align256((size_t)N * 32 * 2);  // h~0 [N,32] fp16

    unsigned int* pairBuf = (unsigned int*)region1;  // 19.2 MB < 25.6 MB
    float* z2 = region1;                             // [N,64] fp32 (pairBuf dead by layer 2)

    const int B = 256;

    k_initcur<<<1, NBMAX, 0, stream>>>(bcur);
    {
        int nblk = (E + B * 32 - 1) / (B * 32);  // 391
        k_passA<<<nblk, B, 0, stream>>>(ei, bcur, pairBuf, E);
    }
    k_passB<<<NB, B, 0, stream>>>(bcur, pairBuf, rowPtr, dis, srcIdx,
                                  x, w_node, b_node, h0h, N, E);

    // layer 1: fp16 64B-row gather + fused @w1 -> fp16 h~1
    k_agg32f<<<(N * 64 + B - 1) / B, B, 0, stream>>>(rowPtr, srcIdx, h0h, dis,
                                                     w1, b1, hT1, N);

    // layer 2: fp16 128B-row gather -> fp32 z2
    k_agg64h<<<(N * 64 + B - 1) / B, B, 0, stream>>>(rowPtr, srcIdx, hT1, dis, z2, N);

    // fused h2-compute + mean-pool + head
    k_poolhead<<<G, B, 0, stream>>>(z2, w2, b2, batch, wf1, bf1, wf2, bf2, out, N);
}